// Round 1
// baseline (282.238 us; speedup 1.0000x reference)
//
#include <hip/hip_runtime.h>

// ---------- types ----------
typedef __bf16 b16x8 __attribute__((ext_vector_type(8)));
typedef float f32x4 __attribute__((ext_vector_type(4)));

static __device__ __forceinline__ f32x4 mfma16(b16x8 a, b16x8 b, f32x4 c) {
  return __builtin_amdgcn_mfma_f32_16x16x32_bf16(a, b, c, 0, 0, 0);
}

// f32 -> bf16 RNE (values are finite; no NaN handling needed)
static __device__ __forceinline__ unsigned short f2bf(float f) {
  unsigned u = __builtin_bit_cast(unsigned, f);
  u += 0x7fffu + ((u >> 16) & 1u);
  return (unsigned short)(u >> 16);
}

static __device__ __forceinline__ void gload16(const void* g, void* s) {
  __builtin_amdgcn_global_load_lds((const __attribute__((address_space(1))) void*)g,
                                   (__attribute__((address_space(3))) void*)s, 16, 0, 0);
}

// ---------- elementwise f32 -> bf16 (8 elems/thread) ----------
__global__ __launch_bounds__(256) void cvt_x(const float* __restrict__ in,
                                             unsigned short* __restrict__ out, int n8) {
  int i = blockIdx.x * 256 + threadIdx.x;
  if (i >= n8) return;
  const float4* p = (const float4*)in + (size_t)2 * i;
  float4 a = p[0], b = p[1];
  unsigned r0 = f2bf(a.x) | ((unsigned)f2bf(a.y) << 16);
  unsigned r1 = f2bf(a.z) | ((unsigned)f2bf(a.w) << 16);
  unsigned r2 = f2bf(b.x) | ((unsigned)f2bf(b.y) << 16);
  unsigned r3 = f2bf(b.z) | ((unsigned)f2bf(b.w) << 16);
  ((uint4*)out)[i] = make_uint4(r0, r1, r2, r3);
}

// ---------- transpose + convert: in[R][C] f32 -> out[C][R] bf16 ----------
__global__ __launch_bounds__(256) void tr_w(const float* __restrict__ in,
                                            unsigned short* __restrict__ out, int R, int C) {
  int idx = blockIdx.x * 256 + threadIdx.x;
  if (idx >= R * C) return;
  int r = idx / C, c = idx % C;
  out[(size_t)c * R + r] = f2bf(in[idx]);
}

// ---------- GEMM: C[M][N] = A[M][K] * Bt[N][K]^T + bias ----------
// 128x128 tile, BK=64, 4 waves (2x2), 16x16x32 MFMA, swizzled LDS (m97 structure).
template <int OUT_F32>
__global__ __launch_bounds__(256) void gemm_bt_bias(const unsigned short* __restrict__ A,
                                                    const unsigned short* __restrict__ Bt,
                                                    const float* __restrict__ bias,
                                                    void* __restrict__ Cout, int M, int N, int K) {
  __shared__ unsigned short As[128 * 64];
  __shared__ unsigned short Bs[128 * 64];
  const int tid = threadIdx.x;
  const int w = tid >> 6, l = tid & 63, g = l >> 4, lm = l & 15;
  const int wr = w >> 1, wc = w & 1;
  const int bm = blockIdx.y, bn = blockIdx.x;

  f32x4 acc[4][4];
#pragma unroll
  for (int i = 0; i < 4; ++i)
#pragma unroll
    for (int j = 0; j < 4; ++j) acc[i][j] = {0.f, 0.f, 0.f, 0.f};

  const int Kb = K * 2;  // row stride bytes
  const char* Abase = (const char*)A + (size_t)(bm * 128) * Kb;
  const char* Bbase = (const char*)Bt + (size_t)(bn * 128) * Kb;
  const int lrow = l >> 3;                                    // row within 8-row chunk
  const int srccol = ((l & 7) * 16) ^ (((l >> 3) & 7) << 4);  // inverse-swizzled source col

  for (int kt = 0; kt < K; kt += 64) {
#pragma unroll
    for (int i = w; i < 16; i += 4) {  // 16 chunks of (8 rows x 128B); 4 per wave
      gload16(Abase + (size_t)(i * 8 + lrow) * Kb + kt * 2 + srccol, As + i * 512);
      gload16(Bbase + (size_t)(i * 8 + lrow) * Kb + kt * 2 + srccol, Bs + i * 512);
    }
    __syncthreads();
#pragma unroll
    for (int ks = 0; ks < 2; ++ks) {
      b16x8 af[4], bf[4];
#pragma unroll
      for (int rt = 0; rt < 4; ++rt) {
        int row = wr * 64 + rt * 16 + lm;
        af[rt] = *(const b16x8*)((const char*)As + row * 128 +
                                 (((ks * 64) + g * 16) ^ ((lm & 7) << 4)));
      }
#pragma unroll
      for (int ct = 0; ct < 4; ++ct) {
        int row = wc * 64 + ct * 16 + lm;
        bf[ct] = *(const b16x8*)((const char*)Bs + row * 128 +
                                 (((ks * 64) + g * 16) ^ ((lm & 7) << 4)));
      }
#pragma unroll
      for (int rt = 0; rt < 4; ++rt)
#pragma unroll
        for (int ct = 0; ct < 4; ++ct) acc[rt][ct] = mfma16(af[rt], bf[ct], acc[rt][ct]);
    }
    __syncthreads();
  }

#pragma unroll
  for (int ct = 0; ct < 4; ++ct) {
    int col = bn * 128 + wc * 64 + ct * 16 + lm;
    float bv = bias[col];
#pragma unroll
    for (int rt = 0; rt < 4; ++rt) {
      int row0 = bm * 128 + wr * 64 + rt * 16 + g * 4;
#pragma unroll
      for (int j = 0; j < 4; ++j) {
        float v = acc[rt][ct][j] + bv;
        if (OUT_F32)
          ((float*)Cout)[(size_t)(row0 + j) * N + col] = v;
        else
          ((unsigned short*)Cout)[(size_t)(row0 + j) * N + col] = f2bf(v);
      }
    }
  }
}

// ---------- flash attention ----------
// grid: (qtile 0..7, head 0..7, bt 0..15). 256 thr = 4 waves; wave owns 32 q-rows.
// qkv[16384][1536] bf16 (q|k|v each 512 = 8 heads x 64). out[16384][512] bf16.
__global__ __launch_bounds__(256) void attn_kernel(const unsigned short* __restrict__ qkv,
                                                   unsigned short* __restrict__ out) {
  __shared__ unsigned short Ks[64 * 64];       // K tile, swizzled
  __shared__ unsigned short Vt[64 * 64];       // V^T tile [d][k], swizzled
  __shared__ unsigned short Ps[4 * 32 * 64];   // per-wave P, swizzled

  const int tid = threadIdx.x;
  const int w = tid >> 6, l = tid & 63, g = l >> 4, lm = l & 15;
  const int qt = blockIdx.x, h = blockIdx.y, bt = blockIdx.z;
  const size_t rb = (size_t)bt * 1024;

  // Q fragments in registers for the whole kernel
  b16x8 qf[2][2];
#pragma unroll
  for (int rt = 0; rt < 2; ++rt)
#pragma unroll
    for (int ks = 0; ks < 2; ++ks) {
      int qrow = qt * 128 + w * 32 + rt * 16 + lm;
      qf[rt][ks] = *(const b16x8*)(qkv + (rb + qrow) * 1536 + h * 64 + ks * 32 + g * 8);
    }

  f32x4 o[2][4], mcur[2], lsum[2];
#pragma unroll
  for (int rt = 0; rt < 2; ++rt) {
#pragma unroll
    for (int dt = 0; dt < 4; ++dt) o[rt][dt] = {0.f, 0.f, 0.f, 0.f};
    mcur[rt] = {-1e30f, -1e30f, -1e30f, -1e30f};
    lsum[rt] = {0.f, 0.f, 0.f, 0.f};
  }

  for (int kb = 0; kb < 16; ++kb) {
    const int k0 = kb * 64;
    // stage K: 8 chunks of 8 rows; wave w does chunks 2w, 2w+1 (swizzled source)
#pragma unroll
    for (int ii = 0; ii < 2; ++ii) {
      int i = w * 2 + ii;
      const char* src = (const char*)(qkv + (rb + k0 + i * 8 + (l >> 3)) * 1536 + 512 + h * 64) +
                        (((l & 7) * 16) ^ (((l >> 3) & 7) << 4));
      gload16(src, Ks + i * 512);
    }
    // stage V^T: lane l = key row, wave w handles d = w*16 .. w*16+15
    {
      const unsigned short* vsrc = qkv + (rb + k0 + l) * 1536 + 1024 + h * 64 + w * 16;
      uint4 v0 = *(const uint4*)vsrc;
      uint4 v1 = *(const uint4*)(vsrc + 8);
      unsigned vv[8] = {v0.x, v0.y, v0.z, v0.w, v1.x, v1.y, v1.z, v1.w};
#pragma unroll
      for (int k2 = 0; k2 < 8; ++k2) {
        int d0 = w * 16 + 2 * k2, d1 = d0 + 1;
        *(unsigned short*)((char*)Vt + d0 * 128 + ((2 * l) ^ ((d0 & 7) << 4))) =
            (unsigned short)(vv[k2] & 0xffffu);
        *(unsigned short*)((char*)Vt + d1 * 128 + ((2 * l) ^ ((d1 & 7) << 4))) =
            (unsigned short)(vv[k2] >> 16);
      }
    }
    __syncthreads();

    // QK^T: S[2 rowtiles][4 keytiles], f32x4 each
    f32x4 s[2][4];
#pragma unroll
    for (int rt = 0; rt < 2; ++rt)
#pragma unroll
      for (int kt = 0; kt < 4; ++kt) s[rt][kt] = {0.f, 0.f, 0.f, 0.f};
#pragma unroll
    for (int kt = 0; kt < 4; ++kt)
#pragma unroll
      for (int ks = 0; ks < 2; ++ks) {
        int kr = kt * 16 + lm;
        b16x8 kf = *(const b16x8*)((const char*)Ks + kr * 128 +
                                   (((ks * 64) + g * 16) ^ ((lm & 7) << 4)));
        s[0][kt] = mfma16(qf[0][ks], kf, s[0][kt]);
        s[1][kt] = mfma16(qf[1][ks], kf, s[1][kt]);
      }

    // online softmax (wave-parallel: 16-lane shfl_xor row reductions)
#pragma unroll
    for (int rt = 0; rt < 2; ++rt) {
      f32x4 mx = {-1e30f, -1e30f, -1e30f, -1e30f};
#pragma unroll
      for (int kt = 0; kt < 4; ++kt)
#pragma unroll
        for (int j = 0; j < 4; ++j) {
          float v = s[rt][kt][j] * 0.125f;
          s[rt][kt][j] = v;
          mx[j] = fmaxf(mx[j], v);
        }
#pragma unroll
      for (int off = 1; off < 16; off <<= 1)
#pragma unroll
        for (int j = 0; j < 4; ++j) mx[j] = fmaxf(mx[j], __shfl_xor(mx[j], off));
      f32x4 mnew, resc, rs = {0.f, 0.f, 0.f, 0.f};
#pragma unroll
      for (int j = 0; j < 4; ++j) {
        mnew[j] = fmaxf(mcur[rt][j], mx[j]);
        resc[j] = __expf(mcur[rt][j] - mnew[j]);
      }
#pragma unroll
      for (int kt = 0; kt < 4; ++kt)
#pragma unroll
        for (int j = 0; j < 4; ++j) {
          float p = __expf(s[rt][kt][j] - mnew[j]);
          s[rt][kt][j] = p;
          rs[j] += p;
        }
#pragma unroll
      for (int off = 1; off < 16; off <<= 1)
#pragma unroll
        for (int j = 0; j < 4; ++j) rs[j] += __shfl_xor(rs[j], off);
#pragma unroll
      for (int j = 0; j < 4; ++j) lsum[rt][j] = lsum[rt][j] * resc[j] + rs[j];
#pragma unroll
      for (int dt = 0; dt < 4; ++dt)
#pragma unroll
        for (int j = 0; j < 4; ++j) o[rt][dt][j] *= resc[j];
      mcur[rt] = mnew;
      // write P (bf16) to this wave's LDS region, swizzled
#pragma unroll
      for (int kt = 0; kt < 4; ++kt)
#pragma unroll
        for (int j = 0; j < 4; ++j) {
          int pr = rt * 16 + g * 4 + j;
          int key = kt * 16 + lm;
          *(unsigned short*)((char*)Ps + w * 4096 + pr * 128 + ((2 * key) ^ ((pr & 7) << 4))) =
              f2bf(s[rt][kt][j]);
        }
    }

    // PV: O += P @ V
#pragma unroll
    for (int ks = 0; ks < 2; ++ks) {
      b16x8 pa[2];
#pragma unroll
      for (int rt = 0; rt < 2; ++rt) {
        int pr = rt * 16 + lm;
        pa[rt] = *(const b16x8*)((const char*)Ps + w * 4096 + pr * 128 +
                                 (((ks * 64) + g * 16) ^ ((lm & 7) << 4)));
      }
#pragma unroll
      for (int dt = 0; dt < 4; ++dt) {
        int d = dt * 16 + lm;
        b16x8 vf = *(const b16x8*)((const char*)Vt + d * 128 +
                                   (((ks * 64) + g * 16) ^ ((d & 7) << 4)));
        o[0][dt] = mfma16(pa[0], vf, o[0][dt]);
        o[1][dt] = mfma16(pa[1], vf, o[1][dt]);
      }
    }
    __syncthreads();
  }

  // finalize: O /= l, store bf16 to [row][h*64+d]
#pragma unroll
  for (int rt = 0; rt < 2; ++rt) {
    f32x4 inv;
#pragma unroll
    for (int j = 0; j < 4; ++j) inv[j] = 1.f / lsum[rt][j];
#pragma unroll
    for (int dt = 0; dt < 4; ++dt)
#pragma unroll
      for (int j = 0; j < 4; ++j) {
        int nrow = qt * 128 + w * 32 + rt * 16 + g * 4 + j;
        out[(rb + nrow) * 512 + h * 64 + dt * 16 + lm] = f2bf(o[rt][dt][j] * inv[j]);
      }
  }
}

// ---------- launch ----------
extern "C" void kernel_launch(void* const* d_in, const int* in_sizes, int n_in, void* d_out,
                              int out_size, void* d_ws, size_t ws_size, hipStream_t stream) {
  const float* x = (const float*)d_in[0];      // [16384][512]
  const float* Wqkv = (const float*)d_in[1];   // [512][1536]
  const float* bqkv = (const float*)d_in[2];   // [1536]
  const float* Wproj = (const float*)d_in[3];  // [512][512]
  const float* bproj = (const float*)d_in[4];  // [512]
  float* outp = (float*)d_out;                 // [16384][512] f32

  char* ws = (char*)d_ws;
  unsigned short* xb = (unsigned short*)(ws);                    // 16 MB
  unsigned short* wqkvT = (unsigned short*)(ws + 16777216);      // 1.5 MB  [1536][512]
  unsigned short* wprojT = (unsigned short*)(ws + 18350080);     // 0.5 MB  [512][512]
  unsigned short* qkvb = (unsigned short*)(ws + 18874368);       // 48 MB   [16384][1536]
  unsigned short* attno = (unsigned short*)(ws + 69206016);      // 16 MB   [16384][512]

  cvt_x<<<4096, 256, 0, stream>>>(x, xb, 1048576);
  tr_w<<<3072, 256, 0, stream>>>(Wqkv, wqkvT, 512, 1536);
  tr_w<<<1024, 256, 0, stream>>>(Wproj, wprojT, 512, 512);
  gemm_bt_bias<0><<<dim3(12, 128), 256, 0, stream>>>(xb, wqkvT, bqkv, qkvb, 16384, 1536, 512);
  attn_kernel<<<dim3(8, 8, 16), 256, 0, stream>>>(qkvb, attno);
  gemm_bt_bias<1><<<dim3(4, 128), 256, 0, stream>>>(attno, wprojT, bproj, outp, 16384, 512, 512);
}

// Round 3
// 231.846 us; speedup vs baseline: 1.2174x; 1.2174x over previous
//
#include <hip/hip_runtime.h>

// ---------- types ----------
typedef __bf16 b16x8 __attribute__((ext_vector_type(8)));
typedef float f32x4 __attribute__((ext_vector_type(4)));
typedef float f32x16 __attribute__((ext_vector_type(16)));
typedef unsigned int u32;

static __device__ __forceinline__ f32x4 mfma16(b16x8 a, b16x8 b, f32x4 c) {
  return __builtin_amdgcn_mfma_f32_16x16x32_bf16(a, b, c, 0, 0, 0);
}
static __device__ __forceinline__ f32x16 mfma32(b16x8 a, b16x8 b, f32x16 c) {
  return __builtin_amdgcn_mfma_f32_32x32x16_bf16(a, b, c, 0, 0, 0);
}

// f32 -> bf16 RNE
static __device__ __forceinline__ unsigned short f2bf(float f) {
  unsigned u = __builtin_bit_cast(unsigned, f);
  u += 0x7fffu + ((u >> 16) & 1u);
  return (unsigned short)(u >> 16);
}
// pack two f32 -> u32 of 2 bf16 (RNE): low half = first arg
static __device__ __forceinline__ u32 cvtpk(float lo, float hi) {
  u32 d;
  asm("v_cvt_pk_bf16_f32 %0, %1, %2" : "=v"(d) : "v"(lo), "v"(hi));
  return d;
}

static __device__ __forceinline__ void gload16(const void* g, void* s) {
  __builtin_amdgcn_global_load_lds((const __attribute__((address_space(1))) void*)g,
                                   (__attribute__((address_space(3))) void*)s, 16, 0, 0);
}

// ---------- elementwise f32 -> bf16 (8 elems/thread) ----------
__global__ __launch_bounds__(256) void cvt_x(const float* __restrict__ in,
                                             unsigned short* __restrict__ out, int n8) {
  int i = blockIdx.x * 256 + threadIdx.x;
  if (i >= n8) return;
  const float4* p = (const float4*)in + (size_t)2 * i;
  float4 a = p[0], b = p[1];
  unsigned r0 = f2bf(a.x) | ((unsigned)f2bf(a.y) << 16);
  unsigned r1 = f2bf(a.z) | ((unsigned)f2bf(a.w) << 16);
  unsigned r2 = f2bf(b.x) | ((unsigned)f2bf(b.y) << 16);
  unsigned r3 = f2bf(b.z) | ((unsigned)f2bf(b.w) << 16);
  ((uint4*)out)[i] = make_uint4(r0, r1, r2, r3);
}

// ---------- transpose + convert: in[R][C] f32 -> out[C][R] bf16 ----------
__global__ __launch_bounds__(256) void tr_w(const float* __restrict__ in,
                                            unsigned short* __restrict__ out, int R, int C) {
  int idx = blockIdx.x * 256 + threadIdx.x;
  if (idx >= R * C) return;
  int r = idx / C, c = idx % C;
  out[(size_t)c * R + r] = f2bf(in[idx]);
}

// ---------- GEMM: C[M][N] = A[M][K] * Bt[N][K]^T + bias ----------
// MODE 0: bf16 out.  MODE 2: f32 out.
template <int MODE>
__global__ __launch_bounds__(256) void gemm_bt_bias(const unsigned short* __restrict__ A,
                                                    const unsigned short* __restrict__ Bt,
                                                    const float* __restrict__ bias,
                                                    void* __restrict__ Cout, int M, int N, int K) {
  __shared__ unsigned short As[128 * 64];
  __shared__ unsigned short Bs[128 * 64];
  const int tid = threadIdx.x;
  const int w = tid >> 6, l = tid & 63, g = l >> 4, lm = l & 15;
  const int wr = w >> 1, wc = w & 1;
  const int bm = blockIdx.y, bn = blockIdx.x;

  f32x4 acc[4][4];
#pragma unroll
  for (int i = 0; i < 4; ++i)
#pragma unroll
    for (int j = 0; j < 4; ++j) acc[i][j] = {0.f, 0.f, 0.f, 0.f};

  const int Kb = K * 2;
  const char* Abase = (const char*)A + (size_t)(bm * 128) * Kb;
  const char* Bbase = (const char*)Bt + (size_t)(bn * 128) * Kb;
  const int lrow = l >> 3;
  const int srccol = ((l & 7) * 16) ^ (((l >> 3) & 7) << 4);

  for (int kt = 0; kt < K; kt += 64) {
#pragma unroll
    for (int i = w; i < 16; i += 4) {
      gload16(Abase + (size_t)(i * 8 + lrow) * Kb + kt * 2 + srccol, As + i * 512);
      gload16(Bbase + (size_t)(i * 8 + lrow) * Kb + kt * 2 + srccol, Bs + i * 512);
    }
    __syncthreads();
#pragma unroll
    for (int ks = 0; ks < 2; ++ks) {
      b16x8 af[4], bf[4];
#pragma unroll
      for (int rt = 0; rt < 4; ++rt) {
        int row = wr * 64 + rt * 16 + lm;
        af[rt] = *(const b16x8*)((const char*)As + row * 128 +
                                 (((ks * 64) + g * 16) ^ ((lm & 7) << 4)));
      }
#pragma unroll
      for (int ct = 0; ct < 4; ++ct) {
        int row = wc * 64 + ct * 16 + lm;
        bf[ct] = *(const b16x8*)((const char*)Bs + row * 128 +
                                 (((ks * 64) + g * 16) ^ ((lm & 7) << 4)));
      }
#pragma unroll
      for (int rt = 0; rt < 4; ++rt)
#pragma unroll
        for (int ct = 0; ct < 4; ++ct) acc[rt][ct] = mfma16(af[rt], bf[ct], acc[rt][ct]);
    }
    __syncthreads();
  }

#pragma unroll
  for (int ct = 0; ct < 4; ++ct) {
    int col = bn * 128 + wc * 64 + ct * 16 + lm;
    float bv = bias[col];
#pragma unroll
    for (int rt = 0; rt < 4; ++rt) {
      int row0 = bm * 128 + wr * 64 + rt * 16 + g * 4;
#pragma unroll
      for (int j = 0; j < 4; ++j) {
        float v = acc[rt][ct][j] + bv;
        if (MODE == 2)
          ((float*)Cout)[(size_t)(row0 + j) * N + col] = v;
        else
          ((unsigned short*)Cout)[(size_t)(row0 + j) * N + col] = f2bf(v);
      }
    }
  }
}

// ---------- flash attention: swapped QK^T (mfma32) + round-1-verified PV ----------
// grid: 1024 blocks (XCD-swizzled), 256 thr = 4 waves; wave owns 32 q-rows.
// qkv[16384][1536] bf16 (q|k|v, raw). out[16384][512] bf16.
__global__ __launch_bounds__(256) void attn_kernel(const unsigned short* __restrict__ qkv,
                                                   unsigned short* __restrict__ out) {
  __shared__ unsigned short Ks[64 * 64];      // K tile [k][d], XOR-swizzled rows
  __shared__ unsigned short Vt[64 * 64];      // V^T tile [d][k], XOR-swizzled rows
  __shared__ unsigned short Ps[4 * 32 * 64];  // per-wave P [q][k], XOR-swizzled rows

  const int tid = threadIdx.x;
  const int w = tid >> 6, l = tid & 63, g = l >> 4, lm = l & 15;
  const int lq = l & 31, hi = l >> 5;
  const int id = blockIdx.x;
  const int id2 = (id & 7) * 128 + (id >> 3);  // XCD-contiguous chunks (bijective)
  const int qt = id2 & 7, h = (id2 >> 3) & 7, bt = id2 >> 6;
  const size_t rb = (size_t)bt * 1024;

  // Q fragments for swapped QK^T (B-operand, col = lq): qf[ks] = Q[q][ks*16 + hi*8 ..+8]
  const int qrow_sw = qt * 128 + w * 32 + lq;
  b16x8 qf[4];
#pragma unroll
  for (int ks = 0; ks < 4; ++ks)
    qf[ks] = *(const b16x8*)(qkv + (rb + qrow_sw) * 1536 + h * 64 + ks * 16 + hi * 8);

  // round-1 PV accumulator layout: o[rt][dt], row q = rt*16+g*4+j, col d = dt*16+lm
  f32x4 o[2][4];
#pragma unroll
  for (int rt = 0; rt < 2; ++rt)
#pragma unroll
    for (int dt = 0; dt < 4; ++dt) o[rt][dt] = {0.f, 0.f, 0.f, 0.f};
  float m = -1e30f, lsum = 0.f;  // per-lane softmax state for q = lq

  const int krow_l = l >> 3;
  const int srccol = ((l & 7) * 16) ^ (((l >> 3) & 7) << 4);
  const char* kbase = (const char*)(qkv + rb * 1536 + 512 + (size_t)h * 64);
  const unsigned short* vbase = qkv + rb * 1536 + 1024 + (size_t)h * 64 + w * 16;

  for (int kb = 0; kb < 16; ++kb) {
    const int k0 = kb * 64;
    // stage K (round-1 pattern): 8 chunks of (8 rows x 128B); wave w does chunks 2w,2w+1
#pragma unroll
    for (int ii = 0; ii < 2; ++ii) {
      int i = w * 2 + ii;
      gload16(kbase + (size_t)(k0 + i * 8 + krow_l) * 3072 + srccol, Ks + i * 512);
    }
    // stage V^T (round-1 pattern): lane l = key row, wave w handles d = w*16..+15
    {
      const unsigned short* vsrc = vbase + (size_t)(k0 + l) * 1536;
      uint4 v0 = *(const uint4*)vsrc;
      uint4 v1 = *(const uint4*)(vsrc + 8);
      u32 vv[8] = {v0.x, v0.y, v0.z, v0.w, v1.x, v1.y, v1.z, v1.w};
#pragma unroll
      for (int k2 = 0; k2 < 8; ++k2) {
        int d0 = w * 16 + 2 * k2, d1 = d0 + 1;
        *(unsigned short*)((char*)Vt + d0 * 128 + ((2 * l) ^ ((d0 & 7) << 4))) =
            (unsigned short)(vv[k2] & 0xffffu);
        *(unsigned short*)((char*)Vt + d1 * 128 + ((2 * l) ^ ((d1 & 7) << 4))) =
            (unsigned short)(vv[k2] >> 16);
      }
    }
    __syncthreads();

    // swapped QK^T: S^T = K_tile * Q; lane holds q=lq, reg r -> key = (r&3)+8*(r>>2)+4*hi
    f32x16 s0 = {0.f, 0.f, 0.f, 0.f, 0.f, 0.f, 0.f, 0.f, 0.f, 0.f, 0.f, 0.f, 0.f, 0.f, 0.f, 0.f};
    f32x16 s1 = s0;
#pragma unroll
    for (int ks = 0; ks < 4; ++ks) {
      int co = (ks * 32 + hi * 16) ^ ((lq & 7) << 4);
      b16x8 k0f = *(const b16x8*)((const char*)Ks + lq * 128 + co);
      b16x8 k1f = *(const b16x8*)((const char*)Ks + (32 + lq) * 128 + co);
      s0 = mfma32(k0f, qf[ks], s0);
      s1 = mfma32(k1f, qf[ks], s1);
    }

    // lane-local online softmax (q = lq; only 2 cross-lane shuffles)
    float mx = -1e30f;
#pragma unroll
    for (int r = 0; r < 16; ++r) {
      s0[r] *= 0.125f;
      s1[r] *= 0.125f;
      mx = fmaxf(mx, fmaxf(s0[r], s1[r]));
    }
    mx = fmaxf(mx, __shfl_xor(mx, 32));
    float mn = fmaxf(m, mx);
    float resc = __expf(m - mn);
    m = mn;
#pragma unroll
    for (int r = 0; r < 16; ++r) {
      s0[r] = __expf(s0[r] - mn);
      s1[r] = __expf(s1[r] - mn);
    }
    float a0 = 0.f, a1 = 0.f, a2 = 0.f, a3 = 0.f;
#pragma unroll
    for (int r = 0; r < 16; r += 4) {
      a0 += s0[r]; a1 += s0[r + 1]; a2 += s0[r + 2]; a3 += s0[r + 3];
      a0 += s1[r]; a1 += s1[r + 1]; a2 += s1[r + 2]; a3 += s1[r + 3];
    }
    float rs = (a0 + a1) + (a2 + a3);
    rs += __shfl_xor(rs, 32);
    lsum = lsum * resc + rs;

    // redistribute resc to o-layout (q = rt*16+g*4+j lives at lane q, hi=0)
#pragma unroll
    for (int rt = 0; rt < 2; ++rt) {
      float r0 = __shfl(resc, rt * 16 + g * 4 + 0);
      float r1 = __shfl(resc, rt * 16 + g * 4 + 1);
      float r2 = __shfl(resc, rt * 16 + g * 4 + 2);
      float r3 = __shfl(resc, rt * 16 + g * 4 + 3);
#pragma unroll
      for (int dt = 0; dt < 4; ++dt) {
        o[rt][dt][0] *= r0;
        o[rt][dt][1] *= r1;
        o[rt][dt][2] *= r2;
        o[rt][dt][3] *= r3;
      }
    }

    // P-write: packed u32 pairs (keys 2k,2k+1) into per-wave Ps[q=lq][key], swizzled
#pragma unroll
    for (int i = 0; i < 8; ++i) {
      int key0 = ((2 * i) & 3) + 8 * (i >> 1) + 4 * hi;  // crow(2i,hi)
      char* prow = (char*)Ps + w * 4096 + lq * 128;
      *(u32*)(prow + ((2 * key0) ^ ((lq & 7) << 4))) = cvtpk(s0[2 * i], s0[2 * i + 1]);
      *(u32*)(prow + ((64 + 2 * key0) ^ ((lq & 7) << 4))) = cvtpk(s1[2 * i], s1[2 * i + 1]);
    }

    // PV (round-1 verbatim): O += P @ V
#pragma unroll
    for (int ks = 0; ks < 2; ++ks) {
      b16x8 pa[2];
#pragma unroll
      for (int rt = 0; rt < 2; ++rt) {
        int pr = rt * 16 + lm;
        pa[rt] = *(const b16x8*)((const char*)Ps + w * 4096 + pr * 128 +
                                 (((ks * 64) + g * 16) ^ ((lm & 7) << 4)));
      }
#pragma unroll
      for (int dt = 0; dt < 4; ++dt) {
        int d = dt * 16 + lm;
        b16x8 vf = *(const b16x8*)((const char*)Vt + d * 128 +
                                   (((ks * 64) + g * 16) ^ ((d & 7) << 4)));
        o[0][dt] = mfma16(pa[0], vf, o[0][dt]);
        o[1][dt] = mfma16(pa[1], vf, o[1][dt]);
      }
    }
    __syncthreads();
  }

  // epilogue (round-1 pattern); 1/lsum redistributed via shfl
  float inv = 1.0f / lsum;
#pragma unroll
  for (int rt = 0; rt < 2; ++rt) {
    float i0 = __shfl(inv, rt * 16 + g * 4 + 0);
    float i1 = __shfl(inv, rt * 16 + g * 4 + 1);
    float i2 = __shfl(inv, rt * 16 + g * 4 + 2);
    float i3 = __shfl(inv, rt * 16 + g * 4 + 3);
    float iv[4] = {i0, i1, i2, i3};
#pragma unroll
    for (int dt = 0; dt < 4; ++dt)
#pragma unroll
      for (int j = 0; j < 4; ++j) {
        int nrow = qt * 128 + w * 32 + rt * 16 + g * 4 + j;
        out[(rb + nrow) * 512 + h * 64 + dt * 16 + lm] = f2bf(o[rt][dt][j] * iv[j]);
      }
  }
}

// ---------- launch ----------
extern "C" void kernel_launch(void* const* d_in, const int* in_sizes, int n_in, void* d_out,
                              int out_size, void* d_ws, size_t ws_size, hipStream_t stream) {
  const float* x = (const float*)d_in[0];      // [16384][512]
  const float* Wqkv = (const float*)d_in[1];   // [512][1536]
  const float* bqkv = (const float*)d_in[2];   // [1536]
  const float* Wproj = (const float*)d_in[3];  // [512][512]
  const float* bproj = (const float*)d_in[4];  // [512]
  float* outp = (float*)d_out;                 // [16384][512] f32

  char* ws = (char*)d_ws;
  unsigned short* xb = (unsigned short*)(ws);                 // 16 MB
  unsigned short* wqkvT = (unsigned short*)(ws + 16777216);   // 1.5 MB [1536][512]
  unsigned short* wprojT = (unsigned short*)(ws + 18350080);  // 0.5 MB [512][512]
  unsigned short* qkvb = (unsigned short*)(ws + 18874368);    // 48 MB  [16384][1536]
  unsigned short* attno = (unsigned short*)(ws + 69206016);   // 16 MB  [16384][512]

  cvt_x<<<4096, 256, 0, stream>>>(x, xb, 1048576);
  tr_w<<<3072, 256, 0, stream>>>(Wqkv, wqkvT, 512, 1536);
  tr_w<<<1024, 256, 0, stream>>>(Wproj, wprojT, 512, 512);
  gemm_bt_bias<0><<<dim3(12, 128), 256, 0, stream>>>(xb, wqkvT, bqkv, qkvb, 16384, 1536, 512);
  attn_kernel<<<1024, 256, 0, stream>>>(qkvb, attno);
  gemm_bt_bias<2><<<dim3(4, 128), 256, 0, stream>>>(attno, wprojT, bproj, outp, 16384, 512, 512);
}